// Round 5
// baseline (3657.991 us; speedup 1.0000x reference)
//
#include <hip/hip_runtime.h>
#include <stdint.h>

#define HOR 128
#define NPATH 4096
#define BATCH 8
#define DM 512
#define H 64
#define BN (BATCH*NPATH)
#define WSTRIDE 516   // j-strip stride in LDS: strip bases hit disjoint bank quads
#define TSTRIDE 132   // padded transpose-row stride

// ---------------- threefry2x32 (JAX-exact) ----------------
__device__ __forceinline__ uint32_t rotl32(uint32_t x, int r) {
  return (x << r) | (x >> (32 - r));
}

__device__ __forceinline__ void tf2x32(uint32_t k0, uint32_t k1,
                                       uint32_t& x0, uint32_t& x1) {
  uint32_t k2 = k0 ^ k1 ^ 0x1BD11BDAu;
  x0 += k0; x1 += k1;
#define TFR4(a,b,c,d) \
  x0 += x1; x1 = rotl32(x1,a); x1 ^= x0; \
  x0 += x1; x1 = rotl32(x1,b); x1 ^= x0; \
  x0 += x1; x1 = rotl32(x1,c); x1 ^= x0; \
  x0 += x1; x1 = rotl32(x1,d); x1 ^= x0;
  TFR4(13,15,26,6)  x0 += k1; x1 += k2 + 1u;
  TFR4(17,29,16,24) x0 += k2; x1 += k0 + 2u;
  TFR4(13,15,26,6)  x0 += k0; x1 += k1 + 3u;
  TFR4(17,29,16,24) x0 += k1; x1 += k2 + 4u;
  TFR4(13,15,26,6)  x0 += k2; x1 += k0 + 5u;
#undef TFR4
}

// ---------------- math helpers ----------------
__device__ __forceinline__ float rcpf(float x) { return __builtin_amdgcn_rcpf(x); }
__device__ __forceinline__ float siluf(float x) {
  return x * rcpf(1.0f + __expf(-x));
}
__device__ __forceinline__ float softplusf(float x) {
  return fmaxf(x, 0.0f) + log1pf(__expf(-fabsf(x)));
}

__device__ __forceinline__ float bits_to_normal(uint32_t bits) {
  uint32_t fb = (bits >> 9) | 0x3F800000u;
  float f = __uint_as_float(fb) - 1.0f;
  float u = fmaf(f, 2.0f, -0.99999994f);
  u = fmaxf(u, -0.99999994f);
  float w = -log1pf(-u * u);
  float p;
  if (w < 5.0f) {
    w = w - 2.5f;
    p = 2.81022636e-08f;
    p = fmaf(p, w, 3.43273939e-07f);
    p = fmaf(p, w, -3.5233877e-06f);
    p = fmaf(p, w, -4.39150654e-06f);
    p = fmaf(p, w, 0.00021858087f);
    p = fmaf(p, w, -0.00125372503f);
    p = fmaf(p, w, -0.00417768164f);
    p = fmaf(p, w, 0.246640727f);
    p = fmaf(p, w, 1.50140941f);
  } else {
    w = sqrtf(w) - 3.0f;
    p = -0.000200214257f;
    p = fmaf(p, w, 0.000100950558f);
    p = fmaf(p, w, 0.00134934322f);
    p = fmaf(p, w, -0.00367342844f);
    p = fmaf(p, w, 0.00573950773f);
    p = fmaf(p, w, -0.0076224613f);
    p = fmaf(p, w, 0.00943887047f);
    p = fmaf(p, w, 1.00167406f);
    p = fmaf(p, w, 2.83297682f);
  }
  return 1.41421356237f * (p * u);
}

// ws layout (floats): [0,512) base_f1[b][j], [512,1024) base_g1[b][j],
// (u32 view) [1024,1152) keyA[t], [1152,1280) keyB[t]

__global__ void k_pre(const float* __restrict__ h_t,
                      const float* __restrict__ W_f1, const float* __restrict__ b_f1,
                      const float* __restrict__ W_g1, const float* __restrict__ b_g1,
                      const float* __restrict__ W_mu, const float* __restrict__ b_mu,
                      const float* __restrict__ W_sig, const float* __restrict__ b_sig,
                      float* __restrict__ out, float* __restrict__ ws) {
  int j = threadIdx.x;           // 0..63
  int b = blockIdx.x;
  if (b == 8) {
    uint32_t* keyA = (uint32_t*)ws + 1024;
    uint32_t* keyB = (uint32_t*)ws + 1152;
    for (int t = j; t < HOR; t += 64) {
      uint32_t x0 = 0u, x1 = (uint32_t)t;
      tf2x32(0u, 42u, x0, x1);
      keyA[t] = x0; keyB[t] = x1;
    }
    return;
  }
  const float* h = h_t + b * DM;
  float accF = b_f1[j], accG = b_g1[j];
  float pm = 0.0f, ps = 0.0f;
  #pragma unroll 4
  for (int d = 0; d < DM; ++d) {
    float hv = h[d];
    accF = fmaf(hv, W_f1[d * H + j], accF);
    accG = fmaf(hv, W_g1[d * H + j], accG);
  }
  ws[b * H + j] = accF;
  ws[512 + b * H + j] = accG;
  for (int d = j; d < DM; d += 64) {
    pm = fmaf(h[d], W_mu[d], pm);
    ps = fmaf(h[d], W_sig[d], ps);
  }
  #pragma unroll
  for (int off = 32; off > 0; off >>= 1) {
    pm += __shfl_down(pm, off);
    ps += __shfl_down(ps, off);
  }
  if (j == 0) {
    out[BN * HOR + b] = pm + b_mu[0];
    out[BN * HOR + 8 + b] = softplusf(ps + b_sig[0]) + 1e-6f;
  }
}

// 8 lanes per path-row; 32 rows per 256-thread block; 1024 blocks.
// Register discipline (rounds 2-4 post-mortems): __launch_bounds__ min-waves
// lets the allocator CHOOSE 4 waves/EU (128 regs) + spills -> GBs of scratch
// traffic. Pin waves_per_eu to exactly 2 (256-reg budget): zero spills; hold
// all per-lane loop-invariant weights in registers (~72) + working set ~100.
__global__ __attribute__((amdgpu_flat_work_group_size(256, 256), amdgpu_waves_per_eu(2, 2)))
void k_sde(const float* __restrict__ ip,
           const float* __restrict__ W_f1, const float* __restrict__ W_f2,
           const float* __restrict__ b_f2, const float* __restrict__ W_f3,
           const float* __restrict__ b_f3, const float* __restrict__ W_g1,
           const float* __restrict__ W_g2, const float* __restrict__ b_g2,
           float* __restrict__ out, const float* __restrict__ ws) {
  __shared__ __align__(16) float sW2[7 * WSTRIDE + 512];  // 8 j-strips, strip q at q*WSTRIDE
  __shared__ __align__(16) float sT[32 * TSTRIDE];        // output transpose buffer
  __shared__ __align__(16) float sF1y[H], sF1t[H], sBF[H];
  __shared__ __align__(16) float sG1y[H], sG1t[H], sBG[H];
  __shared__ __align__(16) float sF3[H], sG2[H], sBf2[H];
  __shared__ uint32_t sKA[HOR], sKB[HOR];

  const int tid = threadIdx.x;
  const int q   = tid & 7;        // lane-slot within row group
  const int rl  = tid >> 3;       // row within block (0..31)
  const int r   = blockIdx.x * 32 + rl;
  const int b   = r >> 12;        // batch (uniform per block: 128 blocks/batch)
  const int lq  = tid & 63;       // lane within wave

  // ---- stage weights ----
  // sW2[(j>>3)*WSTRIDE + (j&7)*64 + k] = W_f2[k][j]
  #pragma unroll
  for (int m = 0; m < 16; ++m) {
    int flat = tid + 256 * m;     // flat = k*64 + j
    sW2[((flat & 63) >> 3) * WSTRIDE + (flat & 7) * 64 + (flat >> 6)] = W_f2[flat];
  }
  if (tid < 64) {
    sF1y[tid] = W_f1[512 * H + tid];
    sF1t[tid] = W_f1[513 * H + tid];
    sG1y[tid] = W_g1[512 * H + tid];
    sG1t[tid] = W_g1[513 * H + tid];
    sF3[tid]  = W_f3[tid];
    sG2[tid]  = W_g2[tid];
    sBf2[tid] = b_f2[tid];
    sBF[tid]  = ws[b * H + tid];
    sBG[tid]  = ws[512 + b * H + tid];
  }
  if (tid >= 64 && tid < 192) {
    const uint32_t* kws = (const uint32_t*)ws;
    int t = tid - 64;
    sKA[t] = kws[1024 + t];
    sKB[t] = kws[1152 + t];
  }
  __syncthreads();

  // per-lane loop-invariant weights -> registers (72 floats; budget is 256)
  float f1y[8], f1t[8], bfv[8], g1y[8], g1t[8], bgv[8], g2v[8], f3v[8], bf2v[8];
  #pragma unroll
  for (int i = 0; i < 8; ++i) {
    int k = q * 8 + i;
    f1y[i] = sF1y[k];  f1t[i] = sF1t[k];  bfv[i] = sBF[k];
    g1y[i] = sG1y[k];  g1t[i] = sG1t[k];  bgv[i] = sBG[k];
    g2v[i] = sG2[k];   f3v[i] = sF3[k];   bf2v[i] = sBf2[k];
  }

  const float bf3 = b_f3[0];
  const float bg2 = b_g2[0];
  float y = logf(ip[b]);
  float z8 = 0.0f;

  #pragma unroll 1
  for (int t = 0; t < HOR; ++t) {
    // one threefry per lane per 8 steps: lane q generates z for step t+q
    if ((t & 7) == 0) {
      int tk = t + q;
      uint32_t x0 = 0u, x1 = (uint32_t)r;
      tf2x32(sKA[tk], sKB[tk], x0, x1);
      z8 = bits_to_normal(x0 ^ x1);
    }
    float z = __shfl(z8, (lq & 56) | (t & 7));
    float tt = (float)t;

    // h1: own 8 units only (k = q*8 + i)
    float h1own[8];
    #pragma unroll
    for (int i = 0; i < 8; ++i) {
      float pre = fmaf(y, f1y[i], fmaf(tt, f1t[i], bfv[i]));
      h1own[i] = siluf(pre);
    }

    // layer 2: lane owns j-strip q (8 accumulators); bb-loop pulls the
    // needed h1 chunk from lane q^bb transiently (numerics = rounds 1-4).
    float a[8];
    #pragma unroll
    for (int jj = 0; jj < 8; ++jj) a[jj] = bf2v[jj];

    #pragma unroll
    for (int bb = 0; bb < 8; ++bb) {
      float hc[8];
      #pragma unroll
      for (int i = 0; i < 8; ++i)
        hc[i] = (bb == 0) ? h1own[i] : __shfl_xor(h1own[i], bb);
      const int kblk = ((q ^ bb) << 3);
      #pragma unroll
      for (int jj = 0; jj < 8; ++jj) {
        int off = q * WSTRIDE + jj * 64 + kblk;
        float4 w0 = *(const float4*)&sW2[off];
        float4 w1 = *(const float4*)&sW2[off + 4];
        a[jj] = fmaf(hc[0], w0.x, a[jj]);
        a[jj] = fmaf(hc[1], w0.y, a[jj]);
        a[jj] = fmaf(hc[2], w0.z, a[jj]);
        a[jj] = fmaf(hc[3], w0.w, a[jj]);
        a[jj] = fmaf(hc[4], w1.x, a[jj]);
        a[jj] = fmaf(hc[5], w1.y, a[jj]);
        a[jj] = fmaf(hc[6], w1.z, a[jj]);
        a[jj] = fmaf(hc[7], w1.w, a[jj]);
      }
    }

    float facc = 0.0f;
    #pragma unroll
    for (int jj = 0; jj < 8; ++jj)
      facc = fmaf(siluf(a[jj]), f3v[jj], facc);
    facc += __shfl_xor(facc, 1);
    facc += __shfl_xor(facc, 2);
    facc += __shfl_xor(facc, 4);

    // g-net: lane owns k-strip q
    float gp = 0.0f;
    #pragma unroll
    for (int i = 0; i < 8; ++i) {
      float pre = fmaf(y, g1y[i], fmaf(tt, g1t[i], bgv[i]));
      gp = fmaf(siluf(pre), g2v[i], gp);
    }
    gp += __shfl_xor(gp, 1);
    gp += __shfl_xor(gp, 2);
    gp += __shfl_xor(gp, 4);
    float g = softplusf(bg2 + gp) + 1e-6f;

    y = (y + (bf3 + facc)) + g * z;   // dt = 1, sqrt_dt = 1
    float yl = fminf(fmaxf(y, -20.0f), 20.0f);
    float e = __expf(yl);
    if (q == (t & 7)) sT[rl * TSTRIDE + t] = e;
  }
  __syncthreads();

  // coalesced block write: rows [blk*32, blk*32+32) are contiguous 16 KB
  float* ob = out + (size_t)blockIdx.x * 4096;
  #pragma unroll
  for (int w = 0; w < 4; ++w) {
    int idx = w * 1024 + tid * 4;
    int row = idx >> 7, col = idx & 127;
    *(float4*)&ob[idx] = *(const float4*)&sT[row * TSTRIDE + col];
  }
}

extern "C" void kernel_launch(void* const* d_in, const int* in_sizes, int n_in,
                              void* d_out, int out_size, void* d_ws, size_t ws_size,
                              hipStream_t stream) {
  const float* h_t   = (const float*)d_in[0];
  const float* ip    = (const float*)d_in[1];
  const float* W_f1  = (const float*)d_in[2];
  const float* b_f1  = (const float*)d_in[3];
  const float* W_f2  = (const float*)d_in[4];
  const float* b_f2  = (const float*)d_in[5];
  const float* W_f3  = (const float*)d_in[6];
  const float* b_f3  = (const float*)d_in[7];
  const float* W_g1  = (const float*)d_in[8];
  const float* b_g1  = (const float*)d_in[9];
  const float* W_g2  = (const float*)d_in[10];
  const float* b_g2  = (const float*)d_in[11];
  const float* W_mu  = (const float*)d_in[12];
  const float* b_mu  = (const float*)d_in[13];
  const float* W_sig = (const float*)d_in[14];
  const float* b_sig = (const float*)d_in[15];
  float* out = (float*)d_out;
  float* ws  = (float*)d_ws;

  hipLaunchKernelGGL(k_pre, dim3(9), dim3(64), 0, stream,
                     h_t, W_f1, b_f1, W_g1, b_g1, W_mu, b_mu, W_sig, b_sig, out, ws);
  hipLaunchKernelGGL(k_sde, dim3(BN / 32), dim3(256), 0, stream,
                     ip, W_f1, W_f2, b_f2, W_f3, b_f3, W_g1, W_g2, b_g2, out, ws);
}

// Round 6
// 1050.880 us; speedup vs baseline: 3.4809x; 3.4809x over previous
//
#include <hip/hip_runtime.h>
#include <stdint.h>

#define HOR 128
#define NPATH 4096
#define BATCH 8
#define DM 512
#define H 64
#define BN (BATCH*NPATH)
#define WSTRIDE 516   // j-strip stride in LDS: strip bases hit disjoint bank quads
#define TSTRIDE 132   // padded transpose-row stride

// ---------------- threefry2x32 (JAX-exact) ----------------
__device__ __forceinline__ uint32_t rotl32(uint32_t x, int r) {
  return (x << r) | (x >> (32 - r));
}

__device__ __forceinline__ void tf2x32(uint32_t k0, uint32_t k1,
                                       uint32_t& x0, uint32_t& x1) {
  uint32_t k2 = k0 ^ k1 ^ 0x1BD11BDAu;
  x0 += k0; x1 += k1;
#define TFR4(a,b,c,d) \
  x0 += x1; x1 = rotl32(x1,a); x1 ^= x0; \
  x0 += x1; x1 = rotl32(x1,b); x1 ^= x0; \
  x0 += x1; x1 = rotl32(x1,c); x1 ^= x0; \
  x0 += x1; x1 = rotl32(x1,d); x1 ^= x0;
  TFR4(13,15,26,6)  x0 += k1; x1 += k2 + 1u;
  TFR4(17,29,16,24) x0 += k2; x1 += k0 + 2u;
  TFR4(13,15,26,6)  x0 += k0; x1 += k1 + 3u;
  TFR4(17,29,16,24) x0 += k1; x1 += k2 + 4u;
  TFR4(13,15,26,6)  x0 += k2; x1 += k0 + 5u;
#undef TFR4
}

// ---------------- math helpers ----------------
__device__ __forceinline__ float rcpf(float x) { return __builtin_amdgcn_rcpf(x); }
__device__ __forceinline__ float siluf(float x) {
  return x * rcpf(1.0f + __expf(-x));
}
__device__ __forceinline__ float softplusf(float x) {
  return fmaxf(x, 0.0f) + log1pf(__expf(-fabsf(x)));
}

__device__ __forceinline__ float bits_to_normal(uint32_t bits) {
  uint32_t fb = (bits >> 9) | 0x3F800000u;
  float f = __uint_as_float(fb) - 1.0f;
  float u = fmaf(f, 2.0f, -0.99999994f);
  u = fmaxf(u, -0.99999994f);
  float w = -log1pf(-u * u);
  float p;
  if (w < 5.0f) {
    w = w - 2.5f;
    p = 2.81022636e-08f;
    p = fmaf(p, w, 3.43273939e-07f);
    p = fmaf(p, w, -3.5233877e-06f);
    p = fmaf(p, w, -4.39150654e-06f);
    p = fmaf(p, w, 0.00021858087f);
    p = fmaf(p, w, -0.00125372503f);
    p = fmaf(p, w, -0.00417768164f);
    p = fmaf(p, w, 0.246640727f);
    p = fmaf(p, w, 1.50140941f);
  } else {
    w = sqrtf(w) - 3.0f;
    p = -0.000200214257f;
    p = fmaf(p, w, 0.000100950558f);
    p = fmaf(p, w, 0.00134934322f);
    p = fmaf(p, w, -0.00367342844f);
    p = fmaf(p, w, 0.00573950773f);
    p = fmaf(p, w, -0.0076224613f);
    p = fmaf(p, w, 0.00943887047f);
    p = fmaf(p, w, 1.00167406f);
    p = fmaf(p, w, 2.83297682f);
  }
  return 1.41421356237f * (p * u);
}

// ws layout (floats): [0,512) base_f1[b][j], [512,1024) base_g1[b][j],
// (u32 view) [1024,1152) keyA[t], [1152,1280) keyB[t]

__global__ void k_pre(const float* __restrict__ h_t,
                      const float* __restrict__ W_f1, const float* __restrict__ b_f1,
                      const float* __restrict__ W_g1, const float* __restrict__ b_g1,
                      const float* __restrict__ W_mu, const float* __restrict__ b_mu,
                      const float* __restrict__ W_sig, const float* __restrict__ b_sig,
                      float* __restrict__ out, float* __restrict__ ws) {
  int j = threadIdx.x;           // 0..63
  int b = blockIdx.x;
  if (b == 8) {
    uint32_t* keyA = (uint32_t*)ws + 1024;
    uint32_t* keyB = (uint32_t*)ws + 1152;
    for (int t = j; t < HOR; t += 64) {
      uint32_t x0 = 0u, x1 = (uint32_t)t;
      tf2x32(0u, 42u, x0, x1);
      keyA[t] = x0; keyB[t] = x1;
    }
    return;
  }
  const float* h = h_t + b * DM;
  float accF = b_f1[j], accG = b_g1[j];
  float pm = 0.0f, ps = 0.0f;
  #pragma unroll 4
  for (int d = 0; d < DM; ++d) {
    float hv = h[d];
    accF = fmaf(hv, W_f1[d * H + j], accF);
    accG = fmaf(hv, W_g1[d * H + j], accG);
  }
  ws[b * H + j] = accF;
  ws[512 + b * H + j] = accG;
  for (int d = j; d < DM; d += 64) {
    pm = fmaf(h[d], W_mu[d], pm);
    ps = fmaf(h[d], W_sig[d], ps);
  }
  #pragma unroll
  for (int off = 32; off > 0; off >>= 1) {
    pm += __shfl_down(pm, off);
    ps += __shfl_down(ps, off);
  }
  if (j == 0) {
    out[BN * HOR + b] = pm + b_mu[0];
    out[BN * HOR + 8 + b] = softplusf(ps + b_sig[0]) + 1e-6f;
  }
}

// 8 lanes per row-PAIR; each lane-group handles rows (rA, rA+32) so every
// W_f2 LDS load is reused for 2 rows (halves DS-pipe W traffic — the R5
// bottleneck). bb-loop is a REAL loop (unroll 1): only one iteration's 16
// b128 loads in flight -> peak live ~85 VGPRs -> no spills at the
// allocator's 128-reg / 4-wave target (R3-R5 post-mortems: never fight the
// allocator with h1[64] or hoisted invariants; it spills to scratch).
__global__ __launch_bounds__(256, 2)
void k_sde(const float* __restrict__ ip,
           const float* __restrict__ W_f1, const float* __restrict__ W_f2,
           const float* __restrict__ b_f2, const float* __restrict__ W_f3,
           const float* __restrict__ b_f3, const float* __restrict__ W_g1,
           const float* __restrict__ W_g2, const float* __restrict__ b_g2,
           float* __restrict__ out, const float* __restrict__ ws) {
  __shared__ __align__(16) float sW2[7 * WSTRIDE + 512];  // 8 j-strips, strip p at p*WSTRIDE
  __shared__ __align__(16) float sT[64 * TSTRIDE];        // output transpose buffer (64 rows)
  __shared__ __align__(16) float sF1y[H], sF1t[H], sBF[H];
  __shared__ __align__(16) float sG1y[H], sG1t[H], sBG[H];
  __shared__ __align__(16) float sF3[H], sG2[H], sBf2[H];
  __shared__ uint32_t sKA[HOR], sKB[HOR];

  const int tid = threadIdx.x;
  const int q   = tid & 7;        // lane-slot within group
  const int g   = tid >> 3;       // group (0..31)
  const int rA  = blockIdx.x * 64 + g;        // 512 blocks x 64 rows
  const int rB  = rA + 32;
  const int b   = blockIdx.x >> 6;            // batch uniform per block
  const int lq  = tid & 63;       // lane within wave

  // ---- stage weights ----
  // sW2[(j>>3)*WSTRIDE + (j&7)*64 + k] = W_f2[k][j]
  #pragma unroll
  for (int m = 0; m < 16; ++m) {
    int flat = tid + 256 * m;     // flat = k*64 + j
    sW2[((flat & 63) >> 3) * WSTRIDE + (flat & 7) * 64 + (flat >> 6)] = W_f2[flat];
  }
  if (tid < 64) {
    sF1y[tid] = W_f1[512 * H + tid];
    sF1t[tid] = W_f1[513 * H + tid];
    sG1y[tid] = W_g1[512 * H + tid];
    sG1t[tid] = W_g1[513 * H + tid];
    sF3[tid]  = W_f3[tid];
    sG2[tid]  = W_g2[tid];
    sBf2[tid] = b_f2[tid];
    sBF[tid]  = ws[b * H + tid];
    sBG[tid]  = ws[512 + b * H + tid];
  }
  if (tid >= 64 && tid < 192) {
    const uint32_t* kws = (const uint32_t*)ws;
    int t = tid - 64;
    sKA[t] = kws[1024 + t];
    sKB[t] = kws[1152 + t];
  }
  __syncthreads();

  const float bf3 = b_f3[0];
  const float bg2 = b_g2[0];
  float yA = logf(ip[b]);
  float yB = yA;
  float zA8 = 0.0f, zB8 = 0.0f;

  #pragma unroll 1
  for (int t = 0; t < HOR; ++t) {
    // one threefry per lane per row per 8 steps
    if ((t & 7) == 0) {
      int tk = t + q;
      uint32_t a0 = 0u, a1 = (uint32_t)rA;
      tf2x32(sKA[tk], sKB[tk], a0, a1);
      zA8 = bits_to_normal(a0 ^ a1);
      uint32_t c0 = 0u, c1 = (uint32_t)rB;
      tf2x32(sKA[tk], sKB[tk], c0, c1);
      zB8 = bits_to_normal(c0 ^ c1);
    }
    const int zsrc = (lq & 56) | (t & 7);
    float zA = __shfl(zA8, zsrc);
    float zB = __shfl(zB8, zsrc);
    float tt = (float)t;

    // h1 own chunks (k = q*8+i) for both rows; invariants via b128 loads
    float h1A[8], h1B[8];
    {
      float4 fy0 = *(const float4*)&sF1y[q * 8], fy1 = *(const float4*)&sF1y[q * 8 + 4];
      float4 ft0 = *(const float4*)&sF1t[q * 8], ft1 = *(const float4*)&sF1t[q * 8 + 4];
      float4 fb0 = *(const float4*)&sBF[q * 8],  fb1 = *(const float4*)&sBF[q * 8 + 4];
      const float fy[8] = {fy0.x,fy0.y,fy0.z,fy0.w,fy1.x,fy1.y,fy1.z,fy1.w};
      const float ft[8] = {ft0.x,ft0.y,ft0.z,ft0.w,ft1.x,ft1.y,ft1.z,ft1.w};
      const float fb[8] = {fb0.x,fb0.y,fb0.z,fb0.w,fb1.x,fb1.y,fb1.z,fb1.w};
      #pragma unroll
      for (int i = 0; i < 8; ++i) {
        float base = fmaf(tt, ft[i], fb[i]);
        h1A[i] = siluf(fmaf(yA, fy[i], base));
        h1B[i] = siluf(fmaf(yB, fy[i], base));
      }
    }

    // accumulators init = b_f2 (same accumulation order as rounds 1-5)
    float aA[8], aB[8];
    {
      float4 b0 = *(const float4*)&sBf2[q * 8], b1 = *(const float4*)&sBf2[q * 8 + 4];
      aA[0]=b0.x; aA[1]=b0.y; aA[2]=b0.z; aA[3]=b0.w;
      aA[4]=b1.x; aA[5]=b1.y; aA[6]=b1.z; aA[7]=b1.w;
      #pragma unroll
      for (int jj = 0; jj < 8; ++jj) aB[jj] = aA[jj];
    }

    // bb = 0 peeled: hc = own chunk
    {
      const float* wb = &sW2[q * WSTRIDE + (q << 3)];
      #pragma unroll
      for (int jj = 0; jj < 8; ++jj) {
        float4 w0 = *(const float4*)&wb[jj * 64];
        float4 w1 = *(const float4*)&wb[jj * 64 + 4];
        aA[jj] = fmaf(h1A[0], w0.x, aA[jj]); aB[jj] = fmaf(h1B[0], w0.x, aB[jj]);
        aA[jj] = fmaf(h1A[1], w0.y, aA[jj]); aB[jj] = fmaf(h1B[1], w0.y, aB[jj]);
        aA[jj] = fmaf(h1A[2], w0.z, aA[jj]); aB[jj] = fmaf(h1B[2], w0.z, aB[jj]);
        aA[jj] = fmaf(h1A[3], w0.w, aA[jj]); aB[jj] = fmaf(h1B[3], w0.w, aB[jj]);
        aA[jj] = fmaf(h1A[4], w1.x, aA[jj]); aB[jj] = fmaf(h1B[4], w1.x, aB[jj]);
        aA[jj] = fmaf(h1A[5], w1.y, aA[jj]); aB[jj] = fmaf(h1B[5], w1.y, aB[jj]);
        aA[jj] = fmaf(h1A[6], w1.z, aA[jj]); aB[jj] = fmaf(h1B[6], w1.z, aB[jj]);
        aA[jj] = fmaf(h1A[7], w1.w, aA[jj]); aB[jj] = fmaf(h1B[7], w1.w, aB[jj]);
      }
    }
    // bb = 1..7: REAL loop (no unroll) — caps in-flight loads & live range
    #pragma unroll 1
    for (int bb = 1; bb < 8; ++bb) {
      float hcA[8], hcB[8];
      #pragma unroll
      for (int i = 0; i < 8; ++i) {
        hcA[i] = __shfl_xor(h1A[i], bb);
        hcB[i] = __shfl_xor(h1B[i], bb);
      }
      const float* wb = &sW2[q * WSTRIDE + ((q ^ bb) << 3)];
      #pragma unroll
      for (int jj = 0; jj < 8; ++jj) {
        float4 w0 = *(const float4*)&wb[jj * 64];
        float4 w1 = *(const float4*)&wb[jj * 64 + 4];
        aA[jj] = fmaf(hcA[0], w0.x, aA[jj]); aB[jj] = fmaf(hcB[0], w0.x, aB[jj]);
        aA[jj] = fmaf(hcA[1], w0.y, aA[jj]); aB[jj] = fmaf(hcB[1], w0.y, aB[jj]);
        aA[jj] = fmaf(hcA[2], w0.z, aA[jj]); aB[jj] = fmaf(hcB[2], w0.z, aB[jj]);
        aA[jj] = fmaf(hcA[3], w0.w, aA[jj]); aB[jj] = fmaf(hcB[3], w0.w, aB[jj]);
        aA[jj] = fmaf(hcA[4], w1.x, aA[jj]); aB[jj] = fmaf(hcB[4], w1.x, aB[jj]);
        aA[jj] = fmaf(hcA[5], w1.y, aA[jj]); aB[jj] = fmaf(hcB[5], w1.y, aB[jj]);
        aA[jj] = fmaf(hcA[6], w1.z, aA[jj]); aB[jj] = fmaf(hcB[6], w1.z, aB[jj]);
        aA[jj] = fmaf(hcA[7], w1.w, aA[jj]); aB[jj] = fmaf(hcB[7], w1.w, aB[jj]);
      }
    }

    // f-head
    float faccA = 0.0f, faccB = 0.0f;
    {
      float4 f30 = *(const float4*)&sF3[q * 8], f31 = *(const float4*)&sF3[q * 8 + 4];
      const float f3[8] = {f30.x,f30.y,f30.z,f30.w,f31.x,f31.y,f31.z,f31.w};
      #pragma unroll
      for (int jj = 0; jj < 8; ++jj) {
        faccA = fmaf(siluf(aA[jj]), f3[jj], faccA);
        faccB = fmaf(siluf(aB[jj]), f3[jj], faccB);
      }
    }
    faccA += __shfl_xor(faccA, 1); faccB += __shfl_xor(faccB, 1);
    faccA += __shfl_xor(faccA, 2); faccB += __shfl_xor(faccB, 2);
    faccA += __shfl_xor(faccA, 4); faccB += __shfl_xor(faccB, 4);

    // g-net
    float gpA = 0.0f, gpB = 0.0f;
    {
      float4 gy0 = *(const float4*)&sG1y[q * 8], gy1 = *(const float4*)&sG1y[q * 8 + 4];
      float4 gt0 = *(const float4*)&sG1t[q * 8], gt1 = *(const float4*)&sG1t[q * 8 + 4];
      float4 gb0 = *(const float4*)&sBG[q * 8],  gb1 = *(const float4*)&sBG[q * 8 + 4];
      float4 g20 = *(const float4*)&sG2[q * 8],  g21 = *(const float4*)&sG2[q * 8 + 4];
      const float gy[8] = {gy0.x,gy0.y,gy0.z,gy0.w,gy1.x,gy1.y,gy1.z,gy1.w};
      const float gt[8] = {gt0.x,gt0.y,gt0.z,gt0.w,gt1.x,gt1.y,gt1.z,gt1.w};
      const float gb[8] = {gb0.x,gb0.y,gb0.z,gb0.w,gb1.x,gb1.y,gb1.z,gb1.w};
      const float g2[8] = {g20.x,g20.y,g20.z,g20.w,g21.x,g21.y,g21.z,g21.w};
      #pragma unroll
      for (int i = 0; i < 8; ++i) {
        float base = fmaf(tt, gt[i], gb[i]);
        gpA = fmaf(siluf(fmaf(yA, gy[i], base)), g2[i], gpA);
        gpB = fmaf(siluf(fmaf(yB, gy[i], base)), g2[i], gpB);
      }
    }
    gpA += __shfl_xor(gpA, 1); gpB += __shfl_xor(gpB, 1);
    gpA += __shfl_xor(gpA, 2); gpB += __shfl_xor(gpB, 2);
    gpA += __shfl_xor(gpA, 4); gpB += __shfl_xor(gpB, 4);
    float gA = softplusf(bg2 + gpA) + 1e-6f;
    float gB = softplusf(bg2 + gpB) + 1e-6f;

    yA = (yA + (bf3 + faccA)) + gA * zA;   // dt = 1, sqrt_dt = 1
    yB = (yB + (bf3 + faccB)) + gB * zB;
    float eA = __expf(fminf(fmaxf(yA, -20.0f), 20.0f));
    float eB = __expf(fminf(fmaxf(yB, -20.0f), 20.0f));
    if (q == (t & 7)) {
      sT[g * TSTRIDE + t] = eA;
      sT[(32 + g) * TSTRIDE + t] = eB;
    }
  }
  __syncthreads();

  // coalesced block write: rows [blk*64, blk*64+64) are contiguous 32 KB
  float* ob = out + (size_t)blockIdx.x * 8192;
  #pragma unroll
  for (int w = 0; w < 8; ++w) {
    int idx = w * 1024 + tid * 4;
    int row = idx >> 7, col = idx & 127;
    *(float4*)&ob[idx] = *(const float4*)&sT[row * TSTRIDE + col];
  }
}

extern "C" void kernel_launch(void* const* d_in, const int* in_sizes, int n_in,
                              void* d_out, int out_size, void* d_ws, size_t ws_size,
                              hipStream_t stream) {
  const float* h_t   = (const float*)d_in[0];
  const float* ip    = (const float*)d_in[1];
  const float* W_f1  = (const float*)d_in[2];
  const float* b_f1  = (const float*)d_in[3];
  const float* W_f2  = (const float*)d_in[4];
  const float* b_f2  = (const float*)d_in[5];
  const float* W_f3  = (const float*)d_in[6];
  const float* b_f3  = (const float*)d_in[7];
  const float* W_g1  = (const float*)d_in[8];
  const float* b_g1  = (const float*)d_in[9];
  const float* W_g2  = (const float*)d_in[10];
  const float* b_g2  = (const float*)d_in[11];
  const float* W_mu  = (const float*)d_in[12];
  const float* b_mu  = (const float*)d_in[13];
  const float* W_sig = (const float*)d_in[14];
  const float* b_sig = (const float*)d_in[15];
  float* out = (float*)d_out;
  float* ws  = (float*)d_ws;

  hipLaunchKernelGGL(k_pre, dim3(9), dim3(64), 0, stream,
                     h_t, W_f1, b_f1, W_g1, b_g1, W_mu, b_mu, W_sig, b_sig, out, ws);
  hipLaunchKernelGGL(k_sde, dim3(BN / 64), dim3(256), 0, stream,
                     ip, W_f1, W_f2, b_f2, W_f3, b_f3, W_g1, W_g2, b_g2, out, ws);
}